// Round 1
// baseline (904.509 us; speedup 1.0000x reference)
//
#include <hip/hip_runtime.h>

typedef unsigned short u16;
typedef __attribute__((ext_vector_type(8))) short bf16x8;
typedef __attribute__((ext_vector_type(4))) float f32x4;

__device__ __forceinline__ u16 f2b(float f) {
  union { float f; unsigned u; } c; c.f = f;
  unsigned u = c.u + 0x7fffu + ((c.u >> 16) & 1u);
  return (u16)(u >> 16);
}
__device__ __forceinline__ float b2f(u16 h) {
  union { unsigned u; float f; } c; c.u = ((unsigned)h) << 16;
  return c.f;
}
__device__ __forceinline__ void g2lds16(const void* g, void* l) {
  __builtin_amdgcn_global_load_lds((const __attribute__((address_space(1))) void*)g,
                                   (__attribute__((address_space(3))) void*)l, 16, 0, 0);
}

// ---------------------------------------------------------------- f32 -> bf16
__global__ __launch_bounds__(256) void cvtk(const float* __restrict__ in,
                                            u16* __restrict__ out, int n4) {
  int i = blockIdx.x * 256 + threadIdx.x;
  if (i < n4) {
    float4 f = ((const float4*)in)[i];
    ushort4 o;
    o.x = f2b(f.x); o.y = f2b(f.y); o.z = f2b(f.z); o.w = f2b(f.w);
    ((ushort4*)out)[i] = o;
  }
}

// ---------------------------------------------------------------- GEMM
// out[m,n] = sum_k A_f32[m,k] * Wbf16[n,k]  (+ bias[n])
// MODE 0: store bf16 to outb
// MODE 1: store f32 to outf
// MODE 2: outf[idx] += (acc + bias) * alpha[n]
// 128x128 tile, BK=64, 4 waves, A reg-staged f32->bf16, B global_load_lds.
// T2 swizzle: LDS byte-in-row ^= (row&7)<<4 on both stage and read.
template<int MODE>
__global__ __launch_bounds__(256)
void gemm_bt(const float* __restrict__ Af, const u16* __restrict__ Bw,
             const float* __restrict__ bias, const float* __restrict__ alpha,
             float* __restrict__ outf, u16* __restrict__ outb, int N, int K)
{
  __shared__ u16 As[128 * 64];
  __shared__ u16 Bs[128 * 64];
  const int tid = threadIdx.x;
  const int wave = tid >> 6, lane = tid & 63;
  const int r16 = lane & 15, rq = lane >> 4;
  const int wr = wave >> 1, wc = wave & 1;
  const long am0 = (long)blockIdx.x * 128;
  const long bn0 = (long)blockIdx.y * 128;

  f32x4 acc[4][4];
  const f32x4 zero = {0.f, 0.f, 0.f, 0.f};
#pragma unroll
  for (int i = 0; i < 4; ++i)
#pragma unroll
    for (int j = 0; j < 4; ++j) acc[i][j] = zero;

  const int nkt = K >> 6;
  for (int kt = 0; kt < nkt; ++kt) {
    // stage A: 1024 chunks of 8 bf16; thread owns chunk c; physical part c&7
    // holds logical part (c&7)^(row&7)
#pragma unroll
    for (int i = 0; i < 4; ++i) {
      int c = i * 256 + tid;
      int row = c >> 3;
      int lp = (c & 7) ^ (row & 7);
      const float* ga = Af + (am0 + row) * (long)K + kt * 64 + lp * 8;
      float4 f0 = ((const float4*)ga)[0];
      float4 f1 = ((const float4*)ga)[1];
      bf16x8 u;
      u[0] = (short)f2b(f0.x); u[1] = (short)f2b(f0.y);
      u[2] = (short)f2b(f0.z); u[3] = (short)f2b(f0.w);
      u[4] = (short)f2b(f1.x); u[5] = (short)f2b(f1.y);
      u[6] = (short)f2b(f1.z); u[7] = (short)f2b(f1.w);
      *(bf16x8*)(As + c * 8) = u;
    }
    // stage B (bf16 weights) via global_load_lds, pre-swizzled source
#pragma unroll
    for (int i = 0; i < 4; ++i) {
      int c = i * 256 + tid;
      int row = c >> 3;
      int lp = (c & 7) ^ (row & 7);
      g2lds16(Bw + (bn0 + row) * (long)K + kt * 64 + lp * 8,
              Bs + (i * 256 + wave * 64) * 8);
    }
    __syncthreads();
#pragma unroll
    for (int kk = 0; kk < 2; ++kk) {
      bf16x8 af[4], bfr[4];
#pragma unroll
      for (int i = 0; i < 4; ++i) {
        int ra = wr * 64 + i * 16 + r16;
        af[i] = *(const bf16x8*)(As + ((ra * 128 + ((kk * 64 + rq * 16) ^ ((ra & 7) << 4))) >> 1));
        int rb = wc * 64 + i * 16 + r16;
        bfr[i] = *(const bf16x8*)(Bs + ((rb * 128 + ((kk * 64 + rq * 16) ^ ((rb & 7) << 4))) >> 1));
      }
#pragma unroll
      for (int i = 0; i < 4; ++i)
#pragma unroll
        for (int j = 0; j < 4; ++j)
          acc[i][j] = __builtin_amdgcn_mfma_f32_16x16x32_bf16(af[i], bfr[j], acc[i][j], 0, 0, 0);
    }
    __syncthreads();
  }

  // epilogue: D row=(lane>>4)*4+r, col=lane&15
#pragma unroll
  for (int j = 0; j < 4; ++j) {
    int col = (int)bn0 + wc * 64 + j * 16 + r16;
    float bb = bias[col];
#pragma unroll
    for (int i = 0; i < 4; ++i) {
      long row = am0 + wr * 64 + i * 16 + rq * 4;
#pragma unroll
      for (int r = 0; r < 4; ++r) {
        float v = acc[i][j][r] + bb;
        long idx = (row + r) * (long)N + col;
        if constexpr (MODE == 0) {
          outb[idx] = f2b(v);
        } else if constexpr (MODE == 1) {
          outf[idx] = v;
        } else {
          outf[idx] += v * alpha[col];
        }
      }
    }
  }
}

// ---------------------------------------------------------------- attention
// One workgroup per (group g, head h). qkv rows indexed via mode mapping:
//   MODE 0 (spatial): row = g*196 + s
//   MODE 1 (th): g=(b,w): row = b*3136 + w + (s/14)*196 + (s%14)*14
//   MODE 2 (tw): g=(b,h'): row = b*3136 + h'*14 + (s/14)*196 + (s%14)
// MODE 2 accumulates (+=) into the fp32 output, others overwrite.
template<int S, int MODE>
__global__ __launch_bounds__(256)
void attn_k(const u16* __restrict__ qkv, float* __restrict__ outp)
{
  constexpr int NT = (S + 15) / 16;   // 13 (S=196) or 14 (S=224)
  constexpr int NB = (NT + 1) / 2;    // 7
  __shared__ u16 Ks[224 * 64];        // K rows, swizzled within 128B rows
  __shared__ u16 Vt[64 * 224];        // V transposed: Vt[d][s]
  __shared__ u16 Ps[4][512];          // per-wave P scratch [16][32]

  const int g = blockIdx.x, h = blockIdx.y;
  const int tid = threadIdx.x;
  const int wave = tid >> 6, lane = tid & 63;
  const int r16 = lane & 15, rq = lane >> 4;

  int base;
  if constexpr (MODE == 0) base = g * 196;
  else if constexpr (MODE == 1) base = (g / 14) * 3136 + (g % 14);
  else base = (g / 14) * 3136 + (g % 14) * 14;

  auto rowof = [&](int s) -> long {
    if constexpr (MODE == 0) return base + s;
    int t = s / 14, u = s % 14;
    return base + t * 196 + u * (MODE == 1 ? 14 : 1);
  };

  // ---- stage K (swizzled, rows clamped) via global_load_lds ----
#pragma unroll
  for (int i = 0; i < 7; ++i) {
    int c = i * 256 + tid;            // 0..1791 = 224 rows x 8 parts
    int s = c >> 3, part = c & 7;
    int sc = (s < S) ? s : (S - 1);
    g2lds16(qkv + rowof(sc) * 2304 + 768 + h * 64 + ((part ^ (s & 7)) << 3),
            &Ks[(i * 256 + wave * 64) * 8]);
  }
  // ---- stage V transposed (zero-filled pad rows) ----
#pragma unroll
  for (int i = 0; i < 7; ++i) {
    int c = i * 256 + tid;
    int s = c >> 3, part = c & 7;
    uint4 v; v.x = 0; v.y = 0; v.z = 0; v.w = 0;
    if (s < S) v = *(const uint4*)(qkv + rowof(s) * 2304 + 1536 + h * 64 + part * 8);
#pragma unroll
    for (int e = 0; e < 4; ++e) {
      unsigned w2 = (&v.x)[e];
      Vt[(part * 8 + 2 * e    ) * 224 + s] = (u16)(w2 & 0xffffu);
      Vt[(part * 8 + 2 * e + 1) * 224 + s] = (u16)(w2 >> 16);
    }
  }
  __syncthreads();

  // ---- per-wave q-tiles (16 rows each) ----
  for (int qt = wave; qt < NT; qt += 4) {
    int q0 = qt * 16;
    int qr = q0 + r16; if (qr > S - 1) qr = S - 1;
    const u16* gq = qkv + rowof(qr) * 2304 + h * 64 + rq * 8;
    bf16x8 aq0 = *(const bf16x8*)(gq);
    bf16x8 aq1 = *(const bf16x8*)(gq + 32);

    float p[4][NT];
#pragma unroll
    for (int kt = 0; kt < NT; ++kt) {
      f32x4 sc4 = {0.f, 0.f, 0.f, 0.f};
      int row = kt * 16 + r16;
      sc4 = __builtin_amdgcn_mfma_f32_16x16x32_bf16(
          aq0, *(const bf16x8*)(Ks + ((row * 128 + ((rq * 16) ^ ((row & 7) << 4))) >> 1)), sc4, 0, 0, 0);
      sc4 = __builtin_amdgcn_mfma_f32_16x16x32_bf16(
          aq1, *(const bf16x8*)(Ks + ((row * 128 + ((64 + rq * 16) ^ ((row & 7) << 4))) >> 1)), sc4, 0, 0, 0);
#pragma unroll
      for (int r = 0; r < 4; ++r) {
        float sv = sc4[r] * 0.125f;
        if (S == 196 && kt == NT - 1) {
          if (kt * 16 + r16 >= S) sv = -1e30f;   // mask padded keys
        }
        p[r][kt] = sv;
      }
    }

    // ---- softmax (rows live in 16-lane groups sharing rq) ----
    float rcp[4];
#pragma unroll
    for (int r = 0; r < 4; ++r) {
      float m = p[r][0];
#pragma unroll
      for (int kt = 1; kt < NT; ++kt) m = fmaxf(m, p[r][kt]);
      m = fmaxf(m, __shfl_xor(m, 1));
      m = fmaxf(m, __shfl_xor(m, 2));
      m = fmaxf(m, __shfl_xor(m, 4));
      m = fmaxf(m, __shfl_xor(m, 8));
      float sum = 0.f;
#pragma unroll
      for (int kt = 0; kt < NT; ++kt) {
        float e = __expf(p[r][kt] - m);
        p[r][kt] = e; sum += e;
      }
      sum += __shfl_xor(sum, 1);
      sum += __shfl_xor(sum, 2);
      sum += __shfl_xor(sum, 4);
      sum += __shfl_xor(sum, 8);
      rcp[r] = 1.f / sum;
    }

    // ---- PV via per-wave LDS round-trip of P ----
    f32x4 oacc[4];
    const f32x4 zero = {0.f, 0.f, 0.f, 0.f};
#pragma unroll
    for (int nt = 0; nt < 4; ++nt) oacc[nt] = zero;
    u16* myP = Ps[wave];
#pragma unroll
    for (int jb = 0; jb < NB; ++jb) {
#pragma unroll
      for (int half = 0; half < 2; ++half) {
        int kt = jb * 2 + half;
#pragma unroll
        for (int r = 0; r < 4; ++r) {
          float pv = (kt < NT) ? p[r][kt] : 0.f;
          myP[(rq * 4 + r) * 32 + half * 16 + r16] = f2b(pv);
        }
      }
      asm volatile("s_waitcnt lgkmcnt(0)" ::: "memory");  // cross-lane: writes visible
      __builtin_amdgcn_sched_barrier(0);
      bf16x8 ap = *(const bf16x8*)(myP + r16 * 32 + rq * 8);
#pragma unroll
      for (int nt = 0; nt < 4; ++nt) {
        bf16x8 bv = *(const bf16x8*)(Vt + (nt * 16 + r16) * 224 + jb * 32 + rq * 8);
        oacc[nt] = __builtin_amdgcn_mfma_f32_16x16x32_bf16(ap, bv, oacc[nt], 0, 0, 0);
      }
      asm volatile("s_waitcnt lgkmcnt(0)" ::: "memory");  // reads done before next overwrite
      __builtin_amdgcn_sched_barrier(0);
    }

    // ---- write out (fp32) ----
#pragma unroll
    for (int r = 0; r < 4; ++r) {
      int q = q0 + rq * 4 + r;
      if (q < S) {
        long orow = rowof(q);
#pragma unroll
        for (int nt = 0; nt < 4; ++nt) {
          float v = oacc[nt][r] * rcp[r];
          long idx = orow * 768 + h * 64 + nt * 16 + r16;
          if constexpr (MODE == 2) outp[idx] += v;
          else outp[idx] = v;
        }
      }
    }
  }
}

// ---------------------------------------------------------------- launch
extern "C" void kernel_launch(void* const* d_in, const int* in_sizes, int n_in,
                              void* d_out, int out_size, void* d_ws, size_t ws_size,
                              hipStream_t stream)
{
  const float* x       = (const float*)d_in[0];
  const float* W_in    = (const float*)d_in[1];
  const float* b_in    = (const float*)d_in[2];
  const float* W_out   = (const float*)d_in[3];
  const float* b_out   = (const float*)d_in[4];
  const float* W_in_t  = (const float*)d_in[5];
  const float* b_in_t  = (const float*)d_in[6];
  const float* W_out_t = (const float*)d_in[7];
  const float* b_out_t = (const float*)d_in[8];
  const float* alpha   = (const float*)d_in[9];
  float* out = (float*)d_out;

  // workspace: 4 bf16 weights (9.4 MB) + qkv/xt bf16 (115.6 MB) + attn-out f32 (77 MB)
  u16* ws    = (u16*)d_ws;
  u16* wib   = ws;                    // 2304*768
  u16* wob   = wib + 1769472;         // 768*768
  u16* witb  = wob + 589824;
  u16* wotb  = witb + 1769472;
  u16* qkvb  = wotb + 589824;         // 25088*2304
  float* aof = (float*)(qkvb + 57802752);  // 25088*768 f32, 16B-aligned offset

  // weight conversions
  cvtk<<<dim3(1728), 256, 0, stream>>>(W_in,    wib,  442368);
  cvtk<<<dim3(576),  256, 0, stream>>>(W_out,   wob,  147456);
  cvtk<<<dim3(1728), 256, 0, stream>>>(W_in_t,  witb, 442368);
  cvtk<<<dim3(576),  256, 0, stream>>>(W_out_t, wotb, 147456);

  // qkv = x @ W_in^T + b_in            [25088 x 2304]
  gemm_bt<0><<<dim3(196, 18), 256, 0, stream>>>(x, wib, b_in, nullptr, nullptr, qkvb, 2304, 768);
  // spatial attention -> aof (f32)
  attn_k<196, 0><<<dim3(128, 12), 256, 0, stream>>>(qkvb, aof);
  // x2 = aof @ W_out^T + b_out -> d_out (f32)
  gemm_bt<1><<<dim3(196, 6), 256, 0, stream>>>(aof, wob, b_out, nullptr, out, nullptr, 768, 768);
  // xt = x2 @ W_in_t^T + b_in_t        [25088 x 2304] (reuse qkvb)
  gemm_bt<0><<<dim3(196, 18), 256, 0, stream>>>(out, witb, b_in_t, nullptr, nullptr, qkvb, 2304, 768);
  // th attention (write), tw attention (accumulate)
  attn_k<224, 1><<<dim3(112, 12), 256, 0, stream>>>(qkvb, aof);
  attn_k<224, 2><<<dim3(112, 12), 256, 0, stream>>>(qkvb, aof);
  // d_out += ((th+tw) @ W_out_t^T + b_out_t) * alpha
  gemm_bt<2><<<dim3(196, 6), 256, 0, stream>>>(aof, wotb, b_out_t, alpha, out, nullptr, 768, 768);
}

// Round 2
// 685.856 us; speedup vs baseline: 1.3188x; 1.3188x over previous
//
#include <hip/hip_runtime.h>

typedef unsigned short u16;
typedef __attribute__((ext_vector_type(8))) short bf16x8;
typedef __attribute__((ext_vector_type(4))) float f32x4;

__device__ __forceinline__ u16 f2b(float f) {
  union { float f; unsigned u; } c; c.f = f;
  unsigned u = c.u + 0x7fffu + ((c.u >> 16) & 1u);
  return (u16)(u >> 16);
}
__device__ __forceinline__ float b2f(u16 h) {
  union { unsigned u; float f; } c; c.u = ((unsigned)h) << 16;
  return c.f;
}
__device__ __forceinline__ void g2lds16(const void* g, void* l) {
  __builtin_amdgcn_global_load_lds((const __attribute__((address_space(1))) void*)g,
                                   (__attribute__((address_space(3))) void*)l, 16, 0, 0);
}

// ---------------------------------------------------------------- f32 -> bf16
__global__ __launch_bounds__(256) void cvtk(const float* __restrict__ in,
                                            u16* __restrict__ out, int n4) {
  int i = blockIdx.x * 256 + threadIdx.x;
  if (i < n4) {
    float4 f = ((const float4*)in)[i];
    ushort4 o;
    o.x = f2b(f.x); o.y = f2b(f.y); o.z = f2b(f.z); o.w = f2b(f.w);
    ((ushort4*)out)[i] = o;
  }
}

// ---------------------------------------------------------------- GEMM
// out[m,n] = sum_k Abf16[m,k] * Wbf16[n,k]  (+ bias[n])
// MODE 0: store bf16 to outb
// MODE 1: store f32 to outf AND bf16 to outb
// MODE 2: A = Aa + Ab2 (two bf16 sources, reg-staged); outf[idx] += (acc+bias)*alpha[n]
// 128x128 tile, BK=64, 4 waves; A,B via global_load_lds (MODE2: A reg-staged).
// T2 swizzle: physical 16B part p of row r holds logical part p^(r&7).
// Grid: 1D, bijective XCD swizzle (nwg%8==0), n-tile fastest within chunk.
template<int MODE>
__global__ __launch_bounds__(256)
void gemm_bt(const u16* __restrict__ Aa, const u16* __restrict__ Ab2,
             const u16* __restrict__ Bw,
             const float* __restrict__ bias, const float* __restrict__ alpha,
             float* __restrict__ outf, u16* __restrict__ outb,
             int N, int K, int NT, int nwg)
{
  __shared__ u16 As[128 * 64];
  __shared__ u16 Bs[128 * 64];
  const int tid = threadIdx.x;
  const int wave = tid >> 6, lane = tid & 63;
  const int r16 = lane & 15, rq = lane >> 4;
  const int wr = wave >> 1, wc = wave & 1;

  // XCD-aware bijective swizzle: same-XCD blocks get a contiguous wg range
  const int q8 = nwg >> 3;
  const int wg = (blockIdx.x & 7) * q8 + (blockIdx.x >> 3);
  const long am0 = (long)(wg / NT) * 128;
  const long bn0 = (long)(wg % NT) * 128;

  f32x4 acc[4][4];
  const f32x4 zero = {0.f, 0.f, 0.f, 0.f};
#pragma unroll
  for (int i = 0; i < 4; ++i)
#pragma unroll
    for (int j = 0; j < 4; ++j) acc[i][j] = zero;

  const int nkt = K >> 6;
  for (int kt = 0; kt < nkt; ++kt) {
#pragma unroll
    for (int i = 0; i < 4; ++i) {
      int c = i * 256 + tid;
      int row = c >> 3;
      int lp = (c & 7) ^ (row & 7);
      if constexpr (MODE == 2) {
        const bf16x8 a1 = *(const bf16x8*)(Aa  + (am0 + row) * (long)K + kt * 64 + lp * 8);
        const bf16x8 a2 = *(const bf16x8*)(Ab2 + (am0 + row) * (long)K + kt * 64 + lp * 8);
        bf16x8 s;
#pragma unroll
        for (int e = 0; e < 8; ++e) s[e] = (short)f2b(b2f((u16)a1[e]) + b2f((u16)a2[e]));
        *(bf16x8*)(As + c * 8) = s;
      } else {
        g2lds16(Aa + (am0 + row) * (long)K + kt * 64 + lp * 8,
                As + (i * 256 + wave * 64) * 8);
      }
      g2lds16(Bw + (bn0 + row) * (long)K + kt * 64 + lp * 8,
              Bs + (i * 256 + wave * 64) * 8);
    }
    __syncthreads();
#pragma unroll
    for (int kk = 0; kk < 2; ++kk) {
      bf16x8 af[4], bfr[4];
#pragma unroll
      for (int i = 0; i < 4; ++i) {
        int ra = wr * 64 + i * 16 + r16;
        af[i] = *(const bf16x8*)(As + ((ra * 128 + ((kk * 64 + rq * 16) ^ ((ra & 7) << 4))) >> 1));
        int rb = wc * 64 + i * 16 + r16;
        bfr[i] = *(const bf16x8*)(Bs + ((rb * 128 + ((kk * 64 + rq * 16) ^ ((rb & 7) << 4))) >> 1));
      }
#pragma unroll
      for (int i = 0; i < 4; ++i)
#pragma unroll
        for (int j = 0; j < 4; ++j)
          acc[i][j] = __builtin_amdgcn_mfma_f32_16x16x32_bf16(af[i], bfr[j], acc[i][j], 0, 0, 0);
    }
    __syncthreads();
  }

  // epilogue: D row=(lane>>4)*4+r, col=lane&15
#pragma unroll
  for (int j = 0; j < 4; ++j) {
    int col = (int)bn0 + wc * 64 + j * 16 + r16;
    float bb = bias[col];
#pragma unroll
    for (int i = 0; i < 4; ++i) {
      long row = am0 + wr * 64 + i * 16 + rq * 4;
#pragma unroll
      for (int r = 0; r < 4; ++r) {
        float v = acc[i][j][r] + bb;
        long idx = (row + r) * (long)N + col;
        if constexpr (MODE == 0) {
          outb[idx] = f2b(v);
        } else if constexpr (MODE == 1) {
          outf[idx] = v;
          outb[idx] = f2b(v);
        } else {
          outf[idx] += v * alpha[col];
        }
      }
    }
  }
}

// ---------------------------------------------------------------- attention
// One workgroup per (group g, head h). qkv rows indexed via mode mapping:
//   MODE 0 (spatial): row = g*196 + s
//   MODE 1 (th): g=(b,w): row = b*3136 + w + (s/14)*196 + (s%14)*14
//   MODE 2 (tw): g=(b,h'): row = b*3136 + h'*14 + (s/14)*196 + (s%14)
// Output: bf16, overwrite.
template<int S, int MODE>
__global__ __launch_bounds__(256)
void attn_k(const u16* __restrict__ qkv, u16* __restrict__ outp)
{
  constexpr int NT = (S + 15) / 16;   // 13 (S=196) or 14 (S=224)
  constexpr int NB = (NT + 1) / 2;    // 7
  __shared__ u16 Ks[224 * 64];        // K rows, swizzled within 128B rows
  __shared__ u16 Vt[64 * 224];        // V transposed: Vt[d][s]
  __shared__ u16 Ps[4][512];          // per-wave P scratch [16][32]

  const int g = blockIdx.x, h = blockIdx.y;
  const int tid = threadIdx.x;
  const int wave = tid >> 6, lane = tid & 63;
  const int r16 = lane & 15, rq = lane >> 4;

  int base;
  if constexpr (MODE == 0) base = g * 196;
  else if constexpr (MODE == 1) base = (g / 14) * 3136 + (g % 14);
  else base = (g / 14) * 3136 + (g % 14) * 14;

  auto rowof = [&](int s) -> long {
    if constexpr (MODE == 0) return base + s;
    int t = s / 14, u = s % 14;
    return base + t * 196 + u * (MODE == 1 ? 14 : 1);
  };

  // ---- stage K (swizzled, rows clamped) via global_load_lds ----
#pragma unroll
  for (int i = 0; i < 7; ++i) {
    int c = i * 256 + tid;            // 0..1791 = 224 rows x 8 parts
    int s = c >> 3, part = c & 7;
    int sc = (s < S) ? s : (S - 1);
    g2lds16(qkv + rowof(sc) * 2304 + 768 + h * 64 + ((part ^ (s & 7)) << 3),
            &Ks[(i * 256 + wave * 64) * 8]);
  }
  // ---- stage V transposed (zero-filled pad rows) ----
#pragma unroll
  for (int i = 0; i < 7; ++i) {
    int c = i * 256 + tid;
    int s = c >> 3, part = c & 7;
    uint4 v; v.x = 0; v.y = 0; v.z = 0; v.w = 0;
    if (s < S) v = *(const uint4*)(qkv + rowof(s) * 2304 + 1536 + h * 64 + part * 8);
#pragma unroll
    for (int e = 0; e < 4; ++e) {
      unsigned w2 = (&v.x)[e];
      Vt[(part * 8 + 2 * e    ) * 224 + s] = (u16)(w2 & 0xffffu);
      Vt[(part * 8 + 2 * e + 1) * 224 + s] = (u16)(w2 >> 16);
    }
  }
  __syncthreads();

  // ---- per-wave q-tiles (16 rows each) ----
  for (int qt = wave; qt < NT; qt += 4) {
    int q0 = qt * 16;
    int qr = q0 + r16; if (qr > S - 1) qr = S - 1;
    const u16* gq = qkv + rowof(qr) * 2304 + h * 64 + rq * 8;
    bf16x8 aq0 = *(const bf16x8*)(gq);
    bf16x8 aq1 = *(const bf16x8*)(gq + 32);

    float p[4][NT];
#pragma unroll
    for (int kt = 0; kt < NT; ++kt) {
      f32x4 sc4 = {0.f, 0.f, 0.f, 0.f};
      int row = kt * 16 + r16;
      sc4 = __builtin_amdgcn_mfma_f32_16x16x32_bf16(
          aq0, *(const bf16x8*)(Ks + ((row * 128 + ((rq * 16) ^ ((row & 7) << 4))) >> 1)), sc4, 0, 0, 0);
      sc4 = __builtin_amdgcn_mfma_f32_16x16x32_bf16(
          aq1, *(const bf16x8*)(Ks + ((row * 128 + ((64 + rq * 16) ^ ((row & 7) << 4))) >> 1)), sc4, 0, 0, 0);
#pragma unroll
      for (int r = 0; r < 4; ++r) {
        float sv = sc4[r] * 0.125f;
        if (S == 196 && kt == NT - 1) {
          if (kt * 16 + r16 >= S) sv = -1e30f;   // mask padded keys
        }
        p[r][kt] = sv;
      }
    }

    // ---- softmax (rows live in 16-lane groups sharing rq) ----
    float rcp[4];
#pragma unroll
    for (int r = 0; r < 4; ++r) {
      float m = p[r][0];
#pragma unroll
      for (int kt = 1; kt < NT; ++kt) m = fmaxf(m, p[r][kt]);
      m = fmaxf(m, __shfl_xor(m, 1));
      m = fmaxf(m, __shfl_xor(m, 2));
      m = fmaxf(m, __shfl_xor(m, 4));
      m = fmaxf(m, __shfl_xor(m, 8));
      float sum = 0.f;
#pragma unroll
      for (int kt = 0; kt < NT; ++kt) {
        float e = __expf(p[r][kt] - m);
        p[r][kt] = e; sum += e;
      }
      sum += __shfl_xor(sum, 1);
      sum += __shfl_xor(sum, 2);
      sum += __shfl_xor(sum, 4);
      sum += __shfl_xor(sum, 8);
      rcp[r] = 1.f / sum;
    }

    // ---- PV via per-wave LDS round-trip of P ----
    f32x4 oacc[4];
    const f32x4 zero = {0.f, 0.f, 0.f, 0.f};
#pragma unroll
    for (int nt = 0; nt < 4; ++nt) oacc[nt] = zero;
    u16* myP = Ps[wave];
#pragma unroll
    for (int jb = 0; jb < NB; ++jb) {
#pragma unroll
      for (int half = 0; half < 2; ++half) {
        int kt = jb * 2 + half;
#pragma unroll
        for (int r = 0; r < 4; ++r) {
          float pv = (kt < NT) ? p[r][kt] : 0.f;
          myP[(rq * 4 + r) * 32 + half * 16 + r16] = f2b(pv);
        }
      }
      asm volatile("s_waitcnt lgkmcnt(0)" ::: "memory");  // cross-lane: writes visible
      __builtin_amdgcn_sched_barrier(0);
      bf16x8 ap = *(const bf16x8*)(myP + r16 * 32 + rq * 8);
#pragma unroll
      for (int nt = 0; nt < 4; ++nt) {
        bf16x8 bv = *(const bf16x8*)(Vt + (nt * 16 + r16) * 224 + jb * 32 + rq * 8);
        oacc[nt] = __builtin_amdgcn_mfma_f32_16x16x32_bf16(ap, bv, oacc[nt], 0, 0, 0);
      }
      asm volatile("s_waitcnt lgkmcnt(0)" ::: "memory");  // reads done before next overwrite
      __builtin_amdgcn_sched_barrier(0);
    }

    // ---- write out (bf16) ----
#pragma unroll
    for (int r = 0; r < 4; ++r) {
      int q = q0 + rq * 4 + r;
      if (q < S) {
        long orow = rowof(q);
#pragma unroll
        for (int nt = 0; nt < 4; ++nt) {
          float v = oacc[nt][r] * rcp[r];
          outp[orow * 768 + h * 64 + nt * 16 + r16] = f2b(v);
        }
      }
    }
  }
}

// ---------------------------------------------------------------- launch
extern "C" void kernel_launch(void* const* d_in, const int* in_sizes, int n_in,
                              void* d_out, int out_size, void* d_ws, size_t ws_size,
                              hipStream_t stream)
{
  const float* x       = (const float*)d_in[0];
  const float* W_in    = (const float*)d_in[1];
  const float* b_in    = (const float*)d_in[2];
  const float* W_out   = (const float*)d_in[3];
  const float* b_out   = (const float*)d_in[4];
  const float* W_in_t  = (const float*)d_in[5];
  const float* b_in_t  = (const float*)d_in[6];
  const float* W_out_t = (const float*)d_in[7];
  const float* b_out_t = (const float*)d_in[8];
  const float* alpha   = (const float*)d_in[9];
  float* out = (float*)d_out;

  // workspace (all u16; 202,113,024 bytes total == round-1 footprint):
  //  weights 9.4 MB | qkvb 115.6 MB | reg1 38.5 MB | reg2 38.5 MB
  //  reg1: xb -> x2ab (spatial attn out) -> th_b
  //  reg2: x2b (bf16 copy of x2)         -> tw_b
  u16* ws    = (u16*)d_ws;
  u16* wib   = ws;                    // 2304*768
  u16* wob   = wib + 1769472;         // 768*768
  u16* witb  = wob + 589824;
  u16* wotb  = witb + 1769472;
  u16* qkvb  = wotb + 589824;         // 25088*2304
  u16* reg1  = qkvb + 57802752;       // 25088*768
  u16* reg2  = reg1 + 19267584;       // 25088*768

  // weight + x conversions
  cvtk<<<dim3(1728),  256, 0, stream>>>(W_in,    wib,  442368);
  cvtk<<<dim3(576),   256, 0, stream>>>(W_out,   wob,  147456);
  cvtk<<<dim3(1728),  256, 0, stream>>>(W_in_t,  witb, 442368);
  cvtk<<<dim3(576),   256, 0, stream>>>(W_out_t, wotb, 147456);
  cvtk<<<dim3(18816), 256, 0, stream>>>(x,       reg1, 4816896);

  // qkv = x @ W_in^T + b_in            [25088 x 2304]
  gemm_bt<0><<<dim3(3528), 256, 0, stream>>>(reg1, nullptr, wib, b_in, nullptr,
                                             nullptr, qkvb, 2304, 768, 18, 3528);
  // spatial attention -> x2ab (bf16, reg1; xb dead)
  attn_k<196, 0><<<dim3(128, 12), 256, 0, stream>>>(qkvb, reg1);
  // x2 = x2ab @ W_out^T + b_out -> d_out (f32) + x2b (bf16, reg2)
  gemm_bt<1><<<dim3(1176), 256, 0, stream>>>(reg1, nullptr, wob, b_out, nullptr,
                                             out, reg2, 768, 768, 6, 1176);
  // xt = x2b @ W_in_t^T + b_in_t       [25088 x 2304] (reuse qkvb)
  gemm_bt<0><<<dim3(3528), 256, 0, stream>>>(reg2, nullptr, witb, b_in_t, nullptr,
                                             nullptr, qkvb, 2304, 768, 18, 3528);
  // th attention -> th_b (reg1), tw attention -> tw_b (reg2)
  attn_k<224, 1><<<dim3(112, 12), 256, 0, stream>>>(qkvb, reg1);
  attn_k<224, 2><<<dim3(112, 12), 256, 0, stream>>>(qkvb, reg2);
  // d_out += ((th_b+tw_b) @ W_out_t^T + b_out_t) * alpha
  gemm_bt<2><<<dim3(1176), 256, 0, stream>>>(reg1, reg2, wotb, b_out_t, alpha,
                                             out, nullptr, 768, 768, 6, 1176);
}

// Round 3
// 648.759 us; speedup vs baseline: 1.3942x; 1.0572x over previous
//
#include <hip/hip_runtime.h>

typedef unsigned short u16;
typedef __attribute__((ext_vector_type(8))) short bf16x8;
typedef __attribute__((ext_vector_type(4))) float f32x4;

__device__ __forceinline__ u16 f2b(float f) {
  union { float f; unsigned u; } c; c.f = f;
  unsigned u = c.u + 0x7fffu + ((c.u >> 16) & 1u);
  return (u16)(u >> 16);
}
__device__ __forceinline__ float b2f(u16 h) {
  union { unsigned u; float f; } c; c.u = ((unsigned)h) << 16;
  return c.f;
}
__device__ __forceinline__ void g2lds16(const void* g, void* l) {
  __builtin_amdgcn_global_load_lds((const __attribute__((address_space(1))) void*)g,
                                   (__attribute__((address_space(3))) void*)l, 16, 0, 0);
}

// ---------------------------------------------------------------- f32 -> bf16
__global__ __launch_bounds__(256) void cvtk(const float* __restrict__ in,
                                            u16* __restrict__ out, int n4) {
  int i = blockIdx.x * 256 + threadIdx.x;
  if (i < n4) {
    float4 f = ((const float4*)in)[i];
    ushort4 o;
    o.x = f2b(f.x); o.y = f2b(f.y); o.z = f2b(f.z); o.w = f2b(f.w);
    ((ushort4*)out)[i] = o;
  }
}

// ---------------------------------------------------------------- GEMM
// out[m,n] = sum_k Abf16[m,k] * Wbf16[n,k]  (+ bias[n])
// MODE 0: store bf16 to outb
// MODE 1: store f32 to outf AND bf16 to outb
// MODE 2: outf[idx] += (acc+bias)*alpha[n]
// 128x128 tile, BK=64, 4 waves; A,B via global_load_lds.
// Double-buffered LDS, raw s_barrier, counted vmcnt(8) (T3+T4): loads for
// tile t+1 stay in flight across the barrier while tile t computes.
// T2 swizzle: physical 16B part p of row r holds logical part p^(r&7).
// Grid: 1D, bijective XCD swizzle (nwg%8==0), n-tile fastest within chunk.
template<int MODE>
__global__ __launch_bounds__(256)
void gemm_bt(const u16* __restrict__ Aa, const u16* __restrict__ Bw,
             const float* __restrict__ bias, const float* __restrict__ alpha,
             float* __restrict__ outf, u16* __restrict__ outb,
             int N, int K, int NT, int nwg)
{
  __shared__ u16 As[2][128 * 64];
  __shared__ u16 Bs[2][128 * 64];
  const int tid = threadIdx.x;
  const int wave = tid >> 6, lane = tid & 63;
  const int r16 = lane & 15, rq = lane >> 4;
  const int wr = wave >> 1, wc = wave & 1;

  // XCD-aware bijective swizzle: same-XCD blocks get a contiguous wg range
  const int q8 = nwg >> 3;
  const int wg = (blockIdx.x & 7) * q8 + (blockIdx.x >> 3);
  const long am0 = (long)(wg / NT) * 128;
  const long bn0 = (long)(wg % NT) * 128;

  f32x4 acc[4][4];
  const f32x4 zero = {0.f, 0.f, 0.f, 0.f};
#pragma unroll
  for (int i = 0; i < 4; ++i)
#pragma unroll
    for (int j = 0; j < 4; ++j) acc[i][j] = zero;

  auto stage = [&](int kt, int buf) {
#pragma unroll
    for (int i = 0; i < 4; ++i) {
      int c = i * 256 + tid;
      int row = c >> 3;
      int lp = (c & 7) ^ (row & 7);
      g2lds16(Aa + (am0 + row) * (long)K + kt * 64 + lp * 8,
              As[buf] + (i * 256 + wave * 64) * 8);
      g2lds16(Bw + (bn0 + row) * (long)K + kt * 64 + lp * 8,
              Bs[buf] + (i * 256 + wave * 64) * 8);
    }
  };

  const int nkt = K >> 6;
  stage(0, 0);
  for (int kt = 0; kt < nkt; ++kt) {
    const int cur = kt & 1;
    if (kt + 1 < nkt) {
      stage(kt + 1, cur ^ 1);
      asm volatile("s_waitcnt vmcnt(8)" ::: "memory");   // tile kt landed; kt+1 in flight
    } else {
      asm volatile("s_waitcnt vmcnt(0)" ::: "memory");
    }
    __builtin_amdgcn_sched_barrier(0);
    __builtin_amdgcn_s_barrier();
    __builtin_amdgcn_sched_barrier(0);
#pragma unroll
    for (int kk = 0; kk < 2; ++kk) {
      bf16x8 af[4], bfr[4];
#pragma unroll
      for (int i = 0; i < 4; ++i) {
        int ra = wr * 64 + i * 16 + r16;
        af[i] = *(const bf16x8*)(As[cur] + ((ra * 128 + ((kk * 64 + rq * 16) ^ ((ra & 7) << 4))) >> 1));
        int rb = wc * 64 + i * 16 + r16;
        bfr[i] = *(const bf16x8*)(Bs[cur] + ((rb * 128 + ((kk * 64 + rq * 16) ^ ((rb & 7) << 4))) >> 1));
      }
#pragma unroll
      for (int i = 0; i < 4; ++i)
#pragma unroll
        for (int j = 0; j < 4; ++j)
          acc[i][j] = __builtin_amdgcn_mfma_f32_16x16x32_bf16(af[i], bfr[j], acc[i][j], 0, 0, 0);
    }
    __builtin_amdgcn_sched_barrier(0);
    __builtin_amdgcn_s_barrier();   // protect As/Bs[cur] before next stage overwrites
    __builtin_amdgcn_sched_barrier(0);
  }

  // epilogue: D row=(lane>>4)*4+r, col=lane&15
#pragma unroll
  for (int j = 0; j < 4; ++j) {
    int col = (int)bn0 + wc * 64 + j * 16 + r16;
    float bb = bias[col];
#pragma unroll
    for (int i = 0; i < 4; ++i) {
      long row = am0 + wr * 64 + i * 16 + rq * 4;
#pragma unroll
      for (int r = 0; r < 4; ++r) {
        float v = acc[i][j][r] + bb;
        long idx = (row + r) * (long)N + col;
        if constexpr (MODE == 0) {
          outb[idx] = f2b(v);
        } else if constexpr (MODE == 1) {
          outf[idx] = v;
          outb[idx] = f2b(v);
        } else {
          outf[idx] += v * alpha[col];
        }
      }
    }
  }
}

// ---------------------------------------------------------------- attention
// One workgroup per (group g, head h). qkv rows indexed via mode mapping:
//   MODE 0 (spatial): row = g*196 + s
//   MODE 1 (th): g=(b,w): row = b*3136 + w + (s/14)*196 + (s%14)*14
//   MODE 2 (tw): g=(b,h'): row = b*3136 + h'*14 + (s/14)*196 + (s%14)
// Output bf16; MODE 2 adds addin[idx] (th result) into its output.
template<int S, int MODE>
__global__ __launch_bounds__(256)
void attn_k(const u16* __restrict__ qkv, const u16* __restrict__ addin,
            u16* __restrict__ outp)
{
  constexpr int NT = (S + 15) / 16;   // 13 (S=196) or 14 (S=224)
  constexpr int NB = (NT + 1) / 2;    // 7
  __shared__ u16 Ks[224 * 64];        // K rows, swizzled within 128B rows
  __shared__ u16 Vt[64 * 224];        // V transposed: Vt[d][s]
  __shared__ u16 Ps[4][512];          // per-wave P scratch [16][32]

  const int g = blockIdx.x, h = blockIdx.y;
  const int tid = threadIdx.x;
  const int wave = tid >> 6, lane = tid & 63;
  const int r16 = lane & 15, rq = lane >> 4;

  int base;
  if constexpr (MODE == 0) base = g * 196;
  else if constexpr (MODE == 1) base = (g / 14) * 3136 + (g % 14);
  else base = (g / 14) * 3136 + (g % 14) * 14;

  auto rowof = [&](int s) -> long {
    if constexpr (MODE == 0) return base + s;
    int t = s / 14, u = s % 14;
    return base + t * 196 + u * (MODE == 1 ? 14 : 1);
  };

  // ---- stage K (swizzled, rows clamped) via global_load_lds ----
#pragma unroll
  for (int i = 0; i < 7; ++i) {
    int c = i * 256 + tid;            // 0..1791 = 224 rows x 8 parts
    int s = c >> 3, part = c & 7;
    int sc = (s < S) ? s : (S - 1);
    g2lds16(qkv + rowof(sc) * 2304 + 768 + h * 64 + ((part ^ (s & 7)) << 3),
            &Ks[(i * 256 + wave * 64) * 8]);
  }
  // ---- stage V transposed (zero-filled pad rows) ----
#pragma unroll
  for (int i = 0; i < 7; ++i) {
    int c = i * 256 + tid;
    int s = c >> 3, part = c & 7;
    uint4 v; v.x = 0; v.y = 0; v.z = 0; v.w = 0;
    if (s < S) v = *(const uint4*)(qkv + rowof(s) * 2304 + 1536 + h * 64 + part * 8);
#pragma unroll
    for (int e = 0; e < 4; ++e) {
      unsigned w2 = (&v.x)[e];
      Vt[(part * 8 + 2 * e    ) * 224 + s] = (u16)(w2 & 0xffffu);
      Vt[(part * 8 + 2 * e + 1) * 224 + s] = (u16)(w2 >> 16);
    }
  }
  __syncthreads();

  // ---- per-wave q-tiles (16 rows each) ----
  for (int qt = wave; qt < NT; qt += 4) {
    int q0 = qt * 16;
    int qr = q0 + r16; if (qr > S - 1) qr = S - 1;
    const u16* gq = qkv + rowof(qr) * 2304 + h * 64 + rq * 8;
    bf16x8 aq0 = *(const bf16x8*)(gq);
    bf16x8 aq1 = *(const bf16x8*)(gq + 32);

    float p[4][NT];
#pragma unroll
    for (int kt = 0; kt < NT; ++kt) {
      f32x4 sc4 = {0.f, 0.f, 0.f, 0.f};
      int row = kt * 16 + r16;
      sc4 = __builtin_amdgcn_mfma_f32_16x16x32_bf16(
          aq0, *(const bf16x8*)(Ks + ((row * 128 + ((rq * 16) ^ ((row & 7) << 4))) >> 1)), sc4, 0, 0, 0);
      sc4 = __builtin_amdgcn_mfma_f32_16x16x32_bf16(
          aq1, *(const bf16x8*)(Ks + ((row * 128 + ((64 + rq * 16) ^ ((row & 7) << 4))) >> 1)), sc4, 0, 0, 0);
#pragma unroll
      for (int r = 0; r < 4; ++r) {
        float sv = sc4[r] * 0.125f;
        if (S == 196 && kt == NT - 1) {
          if (kt * 16 + r16 >= S) sv = -1e30f;   // mask padded keys
        }
        p[r][kt] = sv;
      }
    }

    // ---- softmax (rows live in 16-lane groups sharing rq) ----
    float rcp[4];
#pragma unroll
    for (int r = 0; r < 4; ++r) {
      float m = p[r][0];
#pragma unroll
      for (int kt = 1; kt < NT; ++kt) m = fmaxf(m, p[r][kt]);
      m = fmaxf(m, __shfl_xor(m, 1));
      m = fmaxf(m, __shfl_xor(m, 2));
      m = fmaxf(m, __shfl_xor(m, 4));
      m = fmaxf(m, __shfl_xor(m, 8));
      float sum = 0.f;
#pragma unroll
      for (int kt = 0; kt < NT; ++kt) {
        float e = __expf(p[r][kt] - m);
        p[r][kt] = e; sum += e;
      }
      sum += __shfl_xor(sum, 1);
      sum += __shfl_xor(sum, 2);
      sum += __shfl_xor(sum, 4);
      sum += __shfl_xor(sum, 8);
      rcp[r] = 1.f / sum;
    }

    // ---- PV via per-wave LDS round-trip of P ----
    f32x4 oacc[4];
    const f32x4 zero = {0.f, 0.f, 0.f, 0.f};
#pragma unroll
    for (int nt = 0; nt < 4; ++nt) oacc[nt] = zero;
    u16* myP = Ps[wave];
#pragma unroll
    for (int jb = 0; jb < NB; ++jb) {
#pragma unroll
      for (int half = 0; half < 2; ++half) {
        int kt = jb * 2 + half;
#pragma unroll
        for (int r = 0; r < 4; ++r) {
          float pv = (kt < NT) ? p[r][kt] : 0.f;
          myP[(rq * 4 + r) * 32 + half * 16 + r16] = f2b(pv);
        }
      }
      asm volatile("s_waitcnt lgkmcnt(0)" ::: "memory");  // cross-lane: writes visible
      __builtin_amdgcn_sched_barrier(0);
      bf16x8 ap = *(const bf16x8*)(myP + r16 * 32 + rq * 8);
#pragma unroll
      for (int nt = 0; nt < 4; ++nt) {
        bf16x8 bv = *(const bf16x8*)(Vt + (nt * 16 + r16) * 224 + jb * 32 + rq * 8);
        oacc[nt] = __builtin_amdgcn_mfma_f32_16x16x32_bf16(ap, bv, oacc[nt], 0, 0, 0);
      }
      asm volatile("s_waitcnt lgkmcnt(0)" ::: "memory");  // reads done before next overwrite
      __builtin_amdgcn_sched_barrier(0);
    }

    // ---- write out (bf16); MODE 2 adds th result ----
#pragma unroll
    for (int r = 0; r < 4; ++r) {
      int q = q0 + rq * 4 + r;
      if (q < S) {
        long orow = rowof(q);
#pragma unroll
        for (int nt = 0; nt < 4; ++nt) {
          float v = oacc[nt][r] * rcp[r];
          long idx = orow * 768 + h * 64 + nt * 16 + r16;
          if constexpr (MODE == 2) v += b2f(addin[idx]);
          outp[idx] = f2b(v);
        }
      }
    }
  }
}

// ---------------------------------------------------------------- launch
extern "C" void kernel_launch(void* const* d_in, const int* in_sizes, int n_in,
                              void* d_out, int out_size, void* d_ws, size_t ws_size,
                              hipStream_t stream)
{
  const float* x       = (const float*)d_in[0];
  const float* W_in    = (const float*)d_in[1];
  const float* b_in    = (const float*)d_in[2];
  const float* W_out   = (const float*)d_in[3];
  const float* b_out   = (const float*)d_in[4];
  const float* W_in_t  = (const float*)d_in[5];
  const float* b_in_t  = (const float*)d_in[6];
  const float* W_out_t = (const float*)d_in[7];
  const float* b_out_t = (const float*)d_in[8];
  const float* alpha   = (const float*)d_in[9];
  float* out = (float*)d_out;

  // workspace (all u16; 202,113,024 bytes total):
  //  weights 9.4 MB | qkvb 115.6 MB | reg1 38.5 MB | reg2 38.5 MB
  //  reg1: xb -> x2ab (spatial attn out) -> th_b
  //  reg2: x2b (bf16 copy of x2)         -> (th+tw)_b
  u16* ws    = (u16*)d_ws;
  u16* wib   = ws;                    // 2304*768
  u16* wob   = wib + 1769472;         // 768*768
  u16* witb  = wob + 589824;
  u16* wotb  = witb + 1769472;
  u16* qkvb  = wotb + 589824;         // 25088*2304
  u16* reg1  = qkvb + 57802752;       // 25088*768
  u16* reg2  = reg1 + 19267584;       // 25088*768

  // weight + x conversions
  cvtk<<<dim3(1728),  256, 0, stream>>>(W_in,    wib,  442368);
  cvtk<<<dim3(576),   256, 0, stream>>>(W_out,   wob,  147456);
  cvtk<<<dim3(1728),  256, 0, stream>>>(W_in_t,  witb, 442368);
  cvtk<<<dim3(576),   256, 0, stream>>>(W_out_t, wotb, 147456);
  cvtk<<<dim3(18816), 256, 0, stream>>>(x,       reg1, 4816896);

  // qkv = x @ W_in^T + b_in            [25088 x 2304]
  gemm_bt<0><<<dim3(3528), 256, 0, stream>>>(reg1, wib, b_in, nullptr,
                                             nullptr, qkvb, 2304, 768, 18, 3528);
  // spatial attention -> x2ab (bf16, reg1; xb dead)
  attn_k<196, 0><<<dim3(128, 12), 256, 0, stream>>>(qkvb, nullptr, reg1);
  // x2 = x2ab @ W_out^T + b_out -> d_out (f32) + x2b (bf16, reg2)
  gemm_bt<1><<<dim3(1176), 256, 0, stream>>>(reg1, wob, b_out, nullptr,
                                             out, reg2, 768, 768, 6, 1176);
  // xt = x2b @ W_in_t^T + b_in_t       [25088 x 2304] (reuse qkvb)
  gemm_bt<0><<<dim3(3528), 256, 0, stream>>>(reg2, witb, b_in_t, nullptr,
                                             nullptr, qkvb, 2304, 768, 18, 3528);
  // th attention -> th_b (reg1); tw attention -> reg2 = tw + th
  attn_k<224, 1><<<dim3(112, 12), 256, 0, stream>>>(qkvb, nullptr, reg1);
  attn_k<224, 2><<<dim3(112, 12), 256, 0, stream>>>(qkvb, reg1, reg2);
  // d_out += ((th+tw) @ W_out_t^T + b_out_t) * alpha
  gemm_bt<2><<<dim3(1176), 256, 0, stream>>>(reg2, wotb, b_out_t, alpha,
                                             out, nullptr, 768, 768, 6, 1176);
}